// Round 3
// baseline (108.520 us; speedup 1.0000x reference)
//
#include <hip/hip_runtime.h>

// SeriesDecomp: x (32, 512, 2048) f32. Moving average K=2049, replicate pad p=1024.
// d_out = [x_s (N floats) | x_t (N floats)], x_t = movavg, x_s = x - x_t.
//
// Closed form via row prefix sums (pfx inclusive, epfx exclusive):
//   i <  1024: wsum = (1024-i)*x[0] + pfx[i+1024]
//   i >= 1024: wsum = (i-1023)*x[L-1] + total - epfx[i-1024]   (epfx[0]=0)
//
// Thread t owns elements [8t, 8t+8): loads them (2x float4), scans locally,
// publishes to LDS array w[2048]:
//   t < 128  -> w[8t+d] = epfx[8t+d]   (consumed by i>=1024 branch)
//   t >= 128 -> w[8t+d] = pfx[8t+d]    (consumed by i<1024 branch)
// Consume reads are two aligned ds_read_b128; x for x_s stays in registers;
// stores are nontemporal dwordx4.

#define ROWLEN 2048

typedef float f4 __attribute__((ext_vector_type(4)));   // native vec for builtins

__global__ __launch_bounds__(256) void series_decomp_kernel(
    const float* __restrict__ x,
    float* __restrict__ xs_out,
    float* __restrict__ xt_out)
{
    __shared__ float w[ROWLEN];
    __shared__ float wsum4[4];
    __shared__ float edge[2];   // [0]=x[0], [1]=x[2047]

    const int t = threadIdx.x;
    const size_t rowoff = (size_t)blockIdx.x * ROWLEN;

    // Load 8 contiguous floats (2x dwordx4).
    const f4* xin = reinterpret_cast<const f4*>(x + rowoff);
    const f4 a = xin[2 * t];
    const f4 b = xin[2 * t + 1];

    if (t == 0)   edge[0] = a.x;
    if (t == 255) edge[1] = b.w;

    // In-register inclusive scan of the 8 elements.
    float s0 = a.x;
    float s1 = s0 + a.y;
    float s2 = s1 + a.z;
    float s3 = s2 + a.w;
    float s4 = s3 + b.x;
    float s5 = s4 + b.y;
    float s6 = s5 + b.z;
    float s7 = s6 + b.w;
    const float tot = s7;

    // Wave (64-lane) inclusive shuffle scan of per-thread totals.
    const int lane = t & 63;
    float sc = tot;
    #pragma unroll
    for (int d = 1; d < 64; d <<= 1) {
        float o = __shfl_up(sc, d, 64);
        if (lane >= d) sc += o;
    }
    const int wid = t >> 6;
    if (lane == 63) wsum4[wid] = sc;
    __syncthreads();

    // Exclusive prefix preceding this thread's first element.
    float base = sc - tot;
    #pragma unroll
    for (int ww = 0; ww < 3; ++ww)
        if (ww < wid) base += wsum4[ww];

    // Publish: lower half stores EXCLUSIVE prefix, upper half INCLUSIVE.
    f4 w0, w1;
    if (t < 128) {
        w0 = (f4){base,      base + s0, base + s1, base + s2};
        w1 = (f4){base + s3, base + s4, base + s5, base + s6};
    } else {
        w0 = (f4){base + s0, base + s1, base + s2, base + s3};
        w1 = (f4){base + s4, base + s5, base + s6, base + s7};
    }
    f4* w4 = reinterpret_cast<f4*>(w);
    w4[2 * t]     = w0;
    w4[2 * t + 1] = w1;
    __syncthreads();

    const float x0    = edge[0];
    const float xl    = edge[1];
    const float total = w[ROWLEN - 1];   // pfx[2047] (upper half is inclusive)
    const float invK  = 1.0f / 2049.0f;

    // Fetch the partner prefix block (two aligned ds_read_b128).
    f4 p0, p1;
    if (t < 128) {
        p0 = w4[2 * t + 256];   // pfx[8t+1024 .. +3]
        p1 = w4[2 * t + 257];   // pfx[8t+1028 .. +3]
    } else {
        p0 = w4[2 * t - 256];   // epfx[8t-1024 .. +3]
        p1 = w4[2 * t - 255];
    }

    const int i0 = 8 * t;
    f4 xt0, xt1;
    if (t < 128) {
        xt0.x = ((float)(1024 - (i0 + 0)) * x0 + p0.x) * invK;
        xt0.y = ((float)(1024 - (i0 + 1)) * x0 + p0.y) * invK;
        xt0.z = ((float)(1024 - (i0 + 2)) * x0 + p0.z) * invK;
        xt0.w = ((float)(1024 - (i0 + 3)) * x0 + p0.w) * invK;
        xt1.x = ((float)(1024 - (i0 + 4)) * x0 + p1.x) * invK;
        xt1.y = ((float)(1024 - (i0 + 5)) * x0 + p1.y) * invK;
        xt1.z = ((float)(1024 - (i0 + 6)) * x0 + p1.z) * invK;
        xt1.w = ((float)(1024 - (i0 + 7)) * x0 + p1.w) * invK;
    } else {
        xt0.x = ((float)((i0 + 0) - 1023) * xl + (total - p0.x)) * invK;
        xt0.y = ((float)((i0 + 1) - 1023) * xl + (total - p0.y)) * invK;
        xt0.z = ((float)((i0 + 2) - 1023) * xl + (total - p0.z)) * invK;
        xt0.w = ((float)((i0 + 3) - 1023) * xl + (total - p0.w)) * invK;
        xt1.x = ((float)((i0 + 4) - 1023) * xl + (total - p1.x)) * invK;
        xt1.y = ((float)((i0 + 5) - 1023) * xl + (total - p1.y)) * invK;
        xt1.z = ((float)((i0 + 6) - 1023) * xl + (total - p1.z)) * invK;
        xt1.w = ((float)((i0 + 7) - 1023) * xl + (total - p1.w)) * invK;
    }

    const f4 xs0 = a - xt0;
    const f4 xs1 = b - xt1;

    f4* xs4 = reinterpret_cast<f4*>(xs_out + rowoff);
    f4* xt4 = reinterpret_cast<f4*>(xt_out + rowoff);
    __builtin_nontemporal_store(xs0, &xs4[2 * t]);
    __builtin_nontemporal_store(xs1, &xs4[2 * t + 1]);
    __builtin_nontemporal_store(xt0, &xt4[2 * t]);
    __builtin_nontemporal_store(xt1, &xt4[2 * t + 1]);
}

extern "C" void kernel_launch(void* const* d_in, const int* in_sizes, int n_in,
                              void* d_out, int out_size, void* d_ws, size_t ws_size,
                              hipStream_t stream) {
    const float* x = (const float*)d_in[0];
    const int n = in_sizes[0];              // 32*512*2048
    const int rows = n / ROWLEN;            // 16384
    float* xs = (float*)d_out;              // output 0: seasonal
    float* xt = (float*)d_out + (size_t)n;  // output 1: trend
    series_decomp_kernel<<<rows, 256, 0, stream>>>(x, xs, xt);
}

// Round 4
// 82.386 us; speedup vs baseline: 1.3172x; 1.3172x over previous
//
#include <hip/hip_runtime.h>

// SeriesDecomp: x (32, 512, 2048) f32. Moving average K=2049, replicate pad p=1024.
// d_out = [x_s (N floats) | x_t (N floats)], x_t = movavg, x_s = x - x_t.
//
// Closed form via row prefix sums (pfx inclusive, epfx exclusive):
//   i <  1024: wsum = (1024-i)*x[0] + pfx[i+1024]
//   i >= 1024: wsum = (i-1023)*x[L-1] + total - epfx[i-1024]   (epfx[0]=0)
//
// Thread t owns elements [8t, 8t+8): loads them (2x float4), scans locally,
// publishes to LDS array w[2048]:
//   t < 128  -> w[8t+d] = epfx[8t+d]   (consumed by i>=1024 branch)
//   t >= 128 -> w[8t+d] = pfx[8t+d]    (consumed by i<1024 branch)
// Consume reads are two aligned ds_read_b128; x for x_s stays in registers.
// R4: regular (cached) stores — R3's nontemporal stores regressed 76->108us,
// suspected L2 write-combining bypass.

#define ROWLEN 2048

typedef float f4 __attribute__((ext_vector_type(4)));

__global__ __launch_bounds__(256) void series_decomp_kernel(
    const float* __restrict__ x,
    float* __restrict__ xs_out,
    float* __restrict__ xt_out)
{
    __shared__ float w[ROWLEN];
    __shared__ float wsum4[4];
    __shared__ float edge[2];   // [0]=x[0], [1]=x[2047]

    const int t = threadIdx.x;
    const size_t rowoff = (size_t)blockIdx.x * ROWLEN;

    // Load 8 contiguous floats (2x dwordx4).
    const f4* xin = reinterpret_cast<const f4*>(x + rowoff);
    const f4 a = xin[2 * t];
    const f4 b = xin[2 * t + 1];

    if (t == 0)   edge[0] = a.x;
    if (t == 255) edge[1] = b.w;

    // In-register inclusive scan of the 8 elements.
    float s0 = a.x;
    float s1 = s0 + a.y;
    float s2 = s1 + a.z;
    float s3 = s2 + a.w;
    float s4 = s3 + b.x;
    float s5 = s4 + b.y;
    float s6 = s5 + b.z;
    float s7 = s6 + b.w;
    const float tot = s7;

    // Wave (64-lane) inclusive shuffle scan of per-thread totals.
    const int lane = t & 63;
    float sc = tot;
    #pragma unroll
    for (int d = 1; d < 64; d <<= 1) {
        float o = __shfl_up(sc, d, 64);
        if (lane >= d) sc += o;
    }
    const int wid = t >> 6;
    if (lane == 63) wsum4[wid] = sc;
    __syncthreads();

    // Exclusive prefix preceding this thread's first element.
    float base = sc - tot;
    #pragma unroll
    for (int ww = 0; ww < 3; ++ww)
        if (ww < wid) base += wsum4[ww];

    // Publish: lower half stores EXCLUSIVE prefix, upper half INCLUSIVE.
    f4 w0, w1;
    if (t < 128) {
        w0 = (f4){base,      base + s0, base + s1, base + s2};
        w1 = (f4){base + s3, base + s4, base + s5, base + s6};
    } else {
        w0 = (f4){base + s0, base + s1, base + s2, base + s3};
        w1 = (f4){base + s4, base + s5, base + s6, base + s7};
    }
    f4* w4 = reinterpret_cast<f4*>(w);
    w4[2 * t]     = w0;
    w4[2 * t + 1] = w1;
    __syncthreads();

    const float x0    = edge[0];
    const float xl    = edge[1];
    const float total = w[ROWLEN - 1];   // pfx[2047] (upper half is inclusive)
    const float invK  = 1.0f / 2049.0f;

    // Fetch the partner prefix block (two aligned ds_read_b128).
    f4 p0, p1;
    if (t < 128) {
        p0 = w4[2 * t + 256];   // pfx[8t+1024 .. +3]
        p1 = w4[2 * t + 257];   // pfx[8t+1028 .. +3]
    } else {
        p0 = w4[2 * t - 256];   // epfx[8t-1024 .. +3]
        p1 = w4[2 * t - 255];
    }

    const int i0 = 8 * t;
    f4 xt0, xt1;
    if (t < 128) {
        xt0.x = ((float)(1024 - (i0 + 0)) * x0 + p0.x) * invK;
        xt0.y = ((float)(1024 - (i0 + 1)) * x0 + p0.y) * invK;
        xt0.z = ((float)(1024 - (i0 + 2)) * x0 + p0.z) * invK;
        xt0.w = ((float)(1024 - (i0 + 3)) * x0 + p0.w) * invK;
        xt1.x = ((float)(1024 - (i0 + 4)) * x0 + p1.x) * invK;
        xt1.y = ((float)(1024 - (i0 + 5)) * x0 + p1.y) * invK;
        xt1.z = ((float)(1024 - (i0 + 6)) * x0 + p1.z) * invK;
        xt1.w = ((float)(1024 - (i0 + 7)) * x0 + p1.w) * invK;
    } else {
        xt0.x = ((float)((i0 + 0) - 1023) * xl + (total - p0.x)) * invK;
        xt0.y = ((float)((i0 + 1) - 1023) * xl + (total - p0.y)) * invK;
        xt0.z = ((float)((i0 + 2) - 1023) * xl + (total - p0.z)) * invK;
        xt0.w = ((float)((i0 + 3) - 1023) * xl + (total - p0.w)) * invK;
        xt1.x = ((float)((i0 + 4) - 1023) * xl + (total - p1.x)) * invK;
        xt1.y = ((float)((i0 + 5) - 1023) * xl + (total - p1.y)) * invK;
        xt1.z = ((float)((i0 + 6) - 1023) * xl + (total - p1.z)) * invK;
        xt1.w = ((float)((i0 + 7) - 1023) * xl + (total - p1.w)) * invK;
    }

    const f4 xs0 = a - xt0;
    const f4 xs1 = b - xt1;

    f4* xs4 = reinterpret_cast<f4*>(xs_out + rowoff);
    f4* xt4 = reinterpret_cast<f4*>(xt_out + rowoff);
    xs4[2 * t]     = xs0;
    xs4[2 * t + 1] = xs1;
    xt4[2 * t]     = xt0;
    xt4[2 * t + 1] = xt1;
}

extern "C" void kernel_launch(void* const* d_in, const int* in_sizes, int n_in,
                              void* d_out, int out_size, void* d_ws, size_t ws_size,
                              hipStream_t stream) {
    const float* x = (const float*)d_in[0];
    const int n = in_sizes[0];              // 32*512*2048
    const int rows = n / ROWLEN;            // 16384
    float* xs = (float*)d_out;              // output 0: seasonal
    float* xt = (float*)d_out + (size_t)n;  // output 1: trend
    series_decomp_kernel<<<rows, 256, 0, stream>>>(x, xs, xt);
}

// Round 5
// 81.359 us; speedup vs baseline: 1.3339x; 1.0126x over previous
//
#include <hip/hip_runtime.h>

// SeriesDecomp: x (32, 512, 2048) f32. Moving average K=2049, replicate pad p=1024.
// d_out = [x_s (N floats) | x_t (N floats)], x_t = movavg, x_s = x - x_t.
//
// Wave-per-row, zero LDS, zero barriers. Lane i owns f4 chunks {i, i+64, ...}:
// float f = 256*j + 4*lane + d  (j=0..7, d=0..3).
// The +-1024 partner of slot (j,d) is slot (j+-4,d) of the SAME lane, so the
// closed-form consume is register-local:
//   f <  1024 (j<4):  wsum = (1024-f)*x[0] + pfx(f+1024)
//                     pfx(f+1024) = E[j+4] + ls[j+4][d]
//   f >= 1024 (j>=4): wsum = (f-1023)*x[2047] + total - pfx(f-1025)
//                     pfx(f-1025) = E[j-4] (+ ls[j-4][d-1] for d>=1)
// where ls = per-chunk inclusive scan, E[j] = exclusive prefix of chunk
// (j,lane) in j-major/lane-minor order (8 wave shuffle-scans).

#define ROWLEN 2048

typedef float f4 __attribute__((ext_vector_type(4)));

__global__ __launch_bounds__(256) void series_decomp_kernel(
    const float* __restrict__ x,
    float* __restrict__ xs_out,
    float* __restrict__ xt_out)
{
    const int lane = threadIdx.x & 63;
    const int wid  = threadIdx.x >> 6;
    const int row  = blockIdx.x * 4 + wid;
    const size_t rowoff = (size_t)row * ROWLEN;

    // Coalesced loads: instruction j covers 1KB contiguous.
    const f4* xin = reinterpret_cast<const f4*>(x + rowoff);
    f4 v[8];
    #pragma unroll
    for (int j = 0; j < 8; ++j) v[j] = xin[64 * j + lane];

    // Per-chunk inclusive scans.
    f4 ls[8];
    #pragma unroll
    for (int j = 0; j < 8; ++j) {
        ls[j].x = v[j].x;
        ls[j].y = ls[j].x + v[j].y;
        ls[j].z = ls[j].y + v[j].z;
        ls[j].w = ls[j].z + v[j].w;
    }

    // E[j] = exclusive prefix of chunk (j,lane) in row order; run accumulates
    // full-slot sums S_j. 8 wave scans, fully independent across waves.
    float E[8];
    float run = 0.0f;
    #pragma unroll
    for (int j = 0; j < 8; ++j) {
        const float T = ls[j].w;
        float W = T;
        #pragma unroll
        for (int d = 1; d < 64; d <<= 1) {
            const float o = __shfl_up(W, d, 64);
            if (lane >= d) W += o;
        }
        E[j] = run + (W - T);
        run += __shfl(W, 63, 64);
    }
    const float total = run;
    const float x0 = __shfl(v[0].x, 0, 64);
    const float xl = __shfl(v[7].w, 63, 64);
    const float invK = 1.0f / 2049.0f;

    f4* xs4 = reinterpret_cast<f4*>(xs_out + rowoff);
    f4* xt4 = reinterpret_cast<f4*>(xt_out + rowoff);

    #pragma unroll
    for (int j = 0; j < 4; ++j) {
        // ---- branch A: slot j, floats fb..fb+3 < 1024 ----
        const int fb = 256 * j + 4 * lane;
        f4 xtA;
        xtA.x = ((float)(1024 - (fb + 0)) * x0 + (E[j + 4] + ls[j + 4].x)) * invK;
        xtA.y = ((float)(1024 - (fb + 1)) * x0 + (E[j + 4] + ls[j + 4].y)) * invK;
        xtA.z = ((float)(1024 - (fb + 2)) * x0 + (E[j + 4] + ls[j + 4].z)) * invK;
        xtA.w = ((float)(1024 - (fb + 3)) * x0 + (E[j + 4] + ls[j + 4].w)) * invK;
        const f4 xsA = v[j] - xtA;
        xs4[64 * j + lane] = xsA;
        xt4[64 * j + lane] = xtA;

        // ---- branch B: slot j+4, floats f2..f2+3 >= 1024 ----
        const int f2 = 1024 + fb;
        f4 xtB;
        xtB.x = ((float)(f2 + 0 - 1023) * xl + (total -  E[j]))             * invK;
        xtB.y = ((float)(f2 + 1 - 1023) * xl + (total - (E[j] + ls[j].x))) * invK;
        xtB.z = ((float)(f2 + 2 - 1023) * xl + (total - (E[j] + ls[j].y))) * invK;
        xtB.w = ((float)(f2 + 3 - 1023) * xl + (total - (E[j] + ls[j].z))) * invK;
        const f4 xsB = v[j + 4] - xtB;
        xs4[64 * (j + 4) + lane] = xsB;
        xt4[64 * (j + 4) + lane] = xtB;
    }
}

extern "C" void kernel_launch(void* const* d_in, const int* in_sizes, int n_in,
                              void* d_out, int out_size, void* d_ws, size_t ws_size,
                              hipStream_t stream) {
    const float* x = (const float*)d_in[0];
    const int n = in_sizes[0];              // 32*512*2048
    const int rows = n / ROWLEN;            // 16384
    float* xs = (float*)d_out;              // output 0: seasonal
    float* xt = (float*)d_out + (size_t)n;  // output 1: trend
    series_decomp_kernel<<<rows / 4, 256, 0, stream>>>(x, xs, xt);
}